// Round 6
// baseline (156.532 us; speedup 1.0000x reference)
//
#include <hip/hip_runtime.h>
#include <hip/hip_bf16.h>
#include <stdint.h>

// Problem constants (B=2, S=2048, IN=4096, OUT=4096)
#define MDIM 4096   // B*S
#define NDIM 4096   // OUT
#define KDIM 4096   // IN
#define NT   (KDIM / 64)   // 64 K-tiles of BK=64

typedef __attribute__((ext_vector_type(4))) float  f32x4;
typedef __attribute__((ext_vector_type(8))) short  bf16x8;
typedef __attribute__((ext_vector_type(4))) float  fx4;
typedef __attribute__((ext_vector_type(4))) int    ix4;
typedef __attribute__((ext_vector_type(8))) unsigned short usx8;

__device__ static inline unsigned short f32_to_bf16_rne(float f) {
  union { float f; unsigned int u; } v; v.f = f;
  unsigned int u = v.u;
  u += 0x7fffu + ((u >> 16) & 1u);
  return (unsigned short)(u >> 16);
}

__device__ static inline void gload_lds16(const unsigned short* g, unsigned short* l) {
  __builtin_amdgcn_global_load_lds((const __attribute__((address_space(1))) void*)g,
                                   (__attribute__((address_space(3))) void*)l,
                                   16, 0, 0);
}

// ---------------- merged conversion kernel ----------------

__global__ void cvt_both_kernel(const float* __restrict__ xin,
                                const int* __restrict__ win,
                                unsigned short* __restrict__ xout,
                                unsigned short* __restrict__ wout, int n8each) {
  int idx = blockIdx.x * blockDim.x + threadIdx.x;
  int stride = gridDim.x * blockDim.x;
  for (int i = idx; i < 2 * n8each; i += stride) {
    usx8 r;
    if (i < n8each) {
      const fx4* p = reinterpret_cast<const fx4*>(xin) + (size_t)i * 2;
      fx4 a = p[0], b = p[1];
      r[0] = f32_to_bf16_rne(a[0]); r[1] = f32_to_bf16_rne(a[1]);
      r[2] = f32_to_bf16_rne(a[2]); r[3] = f32_to_bf16_rne(a[3]);
      r[4] = f32_to_bf16_rne(b[0]); r[5] = f32_to_bf16_rne(b[1]);
      r[6] = f32_to_bf16_rne(b[2]); r[7] = f32_to_bf16_rne(b[3]);
      reinterpret_cast<usx8*>(xout)[i] = r;
    } else {
      int j = i - n8each;
      const ix4* p = reinterpret_cast<const ix4*>(win) + (size_t)j * 2;
      ix4 a = p[0], b = p[1];
      r[0] = f32_to_bf16_rne((float)a[0]); r[1] = f32_to_bf16_rne((float)a[1]);
      r[2] = f32_to_bf16_rne((float)a[2]); r[3] = f32_to_bf16_rne((float)a[3]);
      r[4] = f32_to_bf16_rne((float)b[0]); r[5] = f32_to_bf16_rne((float)b[1]);
      r[6] = f32_to_bf16_rne((float)b[2]); r[7] = f32_to_bf16_rne((float)b[3]);
      reinterpret_cast<usx8*>(wout)[j] = r;
    }
  }
}

// ---------------- 256x256 8-phase GEMM (race-fixed fragment mapping) ----------------
// 512 threads = 8 waves (2M x 4N). BK=64. LDS = 2 dbuf x (256x64 A+B) = 128 KiB.
//
// CRITICAL MAPPING RULE (R5 race fix): every wave's phase-1 A reads must lie
// entirely in staging half A0 (rows 0..127) and phase-3 reads in A1 (128..255).
// Wave wr owns split M rows {wr*64..wr*64+63} U {128+wr*64..128+wr*64+63}:
//   a0 rows = wr*64+fr+rb*16 (rb 0..3, half0) ; a1 rows = +128 (rb 8..11, half1).
// B analogous and already safe: wave wc reads B rows [wc*64, wc*64+64);
// wc 0,1 in half0, wc 2,3 in half1 -- ALL B reads complete by Ph2, B staging
// starts Ph3.
// Phase (x8, 2 K-tiles/loop-iter): {subtile ds_reads; stage 1 half-tile;
//   [lgkmcnt(8) if 12 reads]; barrier; lgkmcnt(0); setprio(1); 16 MFMA;
//   setprio(0); barrier} + vmcnt(6) at phases 4/8.
// Stage schedule tile u: Ph1 (u+1,A1) Ph2 (u+2,A0) Ph3 (u+2,B0) Ph4 (u+2,B1).
// Region lifetimes (all readers drained >= one lgkmcnt(0)+barrier earlier):
//   A0[buf u&1]: last read Ph1 (all waves)  -> stage @Ph2 OK
//   B0[buf u&1]: last read Ph1              -> stage @Ph3 OK
//   B1[buf u&1]: last read Ph2              -> stage @Ph4 OK
//   A1[buf u+1&1]: last read tile u-1 Ph3   -> stage @tile-u Ph1 OK
// vmcnt ledger: entering tile u, outstanding = (u+1){A0,B0,B1}=6 loads; tile u
// issues 8; vmcnt(6) at Ph4 forces ALL of tile u+1 landed before its Ph1.
// Tail: tile NT-2 stages only (NT-1,A1), vmcnt(0); tile NT-1 stages nothing.
// LDS swizzle: slot q^(row&7), pre-swizzled global source (conflicts == 0).

__global__ __launch_bounds__(512, 2) void gemm_m201(
    const unsigned short* __restrict__ A,    // [M][K] bf16 bits
    const unsigned short* __restrict__ Bw,   // [N][K] bf16 bits
    const float* __restrict__ scales,
    const float* __restrict__ bias,
    float* __restrict__ C) {
  __shared__ unsigned short Ash[32768];   // [2][256][64]
  __shared__ unsigned short Bsh[32768];

  const int tid = threadIdx.x;
  const int w   = tid >> 6;          // wave 0..7
  const int l   = tid & 63;
  const int wr  = w >> 2;            // 0..1 : M sub-block within each half
  const int wc  = w & 3;             // 0..3 : N quarter
  const int fr  = l & 15;            // fragment row
  const int fq  = l >> 4;            // fragment k-quarter

  // XCD-aware swizzle: 256 blocks, 256 % 8 == 0 -> simple bijective form
  const int id  = blockIdx.x;
  const int swz = (id & 7) * 32 + (id >> 3);
  const int bm  = swz >> 4, bn = swz & 15;

  const unsigned short* aorg = A  + (size_t)(bm * 256) * KDIM;
  const unsigned short* borg = Bw + (size_t)(bn * 256) * KDIM;

  // staging per-thread global offset (pre-swizzled source)
  const int lr = l >> 3;                 // row-in-octet 0..7
  const int ks = (l & 7) ^ lr;           // swizzled k-slot
  const size_t g_off = (size_t)(w * 16 + lr) * KDIM + (size_t)ks * 8;
  const int    s_off = w * 1024;         // lds elems (wave-uniform)

#define STAGE(isB, t, h) do {                                                   \
    const unsigned short* _g = ((isB) ? borg : aorg)                            \
        + (size_t)(h) * 128 * KDIM + (size_t)(t) * 64 + g_off;                  \
    unsigned short* _l = ((isB) ? Bsh : Ash)                                    \
        + (((t) & 1) * 16384 + (h) * 8192 + s_off);                             \
    gload_lds16(_g, _l);                                                        \
    gload_lds16(_g + 8 * KDIM, _l + 512);                                       \
  } while (0)

  // ds_read offsets (swizzled). NOTE split-row mapping (see header comment):
  // arow base covers rows [wr*64, wr*64+64) ; a1 adds 8192 (= +128 rows).
  const int arow = (wr * 64 + fr) * 64;
  const int brow = (wc * 64 + fr) * 64;
  const int q0 = ((fq)     ^ (fr & 7)) * 8;
  const int q1 = ((4 + fq) ^ (fr & 7)) * 8;

#define LDA(off, rb, qq) (*(const bf16x8*)(Ash + (off) + arow + (rb) * 1024 + (qq)))
#define LDB(off, nc, qq) (*(const bf16x8*)(Bsh + (off) + brow + (nc) * 1024 + (qq)))

#define BAR   __builtin_amdgcn_s_barrier()
#define LGKM0 asm volatile("s_waitcnt lgkmcnt(0)" ::: "memory")
#define LGKM8 asm volatile("s_waitcnt lgkmcnt(8)" ::: "memory")
#define VMW6  asm volatile("s_waitcnt vmcnt(6)" ::: "memory")
#define VMW0  asm volatile("s_waitcnt vmcnt(0)" ::: "memory")
#define NOVM  ((void)0)

  f32x4 acc[8][4] = {};
  bf16x8 a0[4][2], a1[4][2], b0[2][2], b1[2][2];

  // a0: rows wr*64+fr+rb*16 (A half0). a1: +128 rows => +8192 elems (rb 8..11).
#define READ_A0(CO) { _Pragma("unroll") for (int rb = 0; rb < 4; ++rb) { a0[rb][0] = LDA(CO, rb, q0);     a0[rb][1] = LDA(CO, rb, q1); } }
#define READ_A1(CO) { _Pragma("unroll") for (int rb = 0; rb < 4; ++rb) { a1[rb][0] = LDA(CO, 8 + rb, q0); a1[rb][1] = LDA(CO, 8 + rb, q1); } }
#define READ_B0(CO) { _Pragma("unroll") for (int cb = 0; cb < 2; ++cb) { b0[cb][0] = LDB(CO, cb, q0);     b0[cb][1] = LDB(CO, cb, q1); } }
#define READ_B1(CO) { _Pragma("unroll") for (int cb = 0; cb < 2; ++cb) { b1[cb][0] = LDB(CO, 2 + cb, q0); b1[cb][1] = LDB(CO, 2 + cb, q1); } }

#define MFMA_Q(MH, NH, AA, BB)                                                  \
  { _Pragma("unroll") for (int rb = 0; rb < 4; ++rb)                            \
    _Pragma("unroll") for (int cb = 0; cb < 2; ++cb) {                          \
      acc[(MH)*4+rb][(NH)*2+cb] = __builtin_amdgcn_mfma_f32_16x16x32_bf16(      \
          AA[rb][0], BB[cb][0], acc[(MH)*4+rb][(NH)*2+cb], 0, 0, 0);            \
      acc[(MH)*4+rb][(NH)*2+cb] = __builtin_amdgcn_mfma_f32_16x16x32_bf16(      \
          AA[rb][1], BB[cb][1], acc[(MH)*4+rb][(NH)*2+cb], 0, 0, 0);            \
    } }

  // TILE: 4 phases for K-tile U with LDS buffer offset CO.
#define TILE(U, CO, S1, S2, VMST) do {                                          \
    /* Ph1: Q(0,0) -- reads A half0 + B(own) */                                 \
    READ_A0(CO); READ_B0(CO);                                                   \
    if (S1) STAGE(0, (U) + 1, 1);                                               \
    LGKM8; BAR; LGKM0;                                                          \
    __builtin_amdgcn_s_setprio(1); MFMA_Q(0, 0, a0, b0);                        \
    __builtin_amdgcn_s_setprio(0); BAR;                                         \
    /* Ph2: Q(0,1) -- last B reads of tile U */                                 \
    READ_B1(CO);                                                                \
    if (S2) STAGE(0, (U) + 2, 0);                                               \
    BAR; LGKM0;                                                                 \
    __builtin_amdgcn_s_setprio(1); MFMA_Q(0, 1, a0, b1);                        \
    __builtin_amdgcn_s_setprio(0); BAR;                                         \
    /* Ph3: Q(1,0) -- reads A half1 */                                          \
    READ_A1(CO);                                                                \
    if (S2) STAGE(1, (U) + 2, 0);                                               \
    BAR; LGKM0;                                                                 \
    __builtin_amdgcn_s_setprio(1); MFMA_Q(1, 0, a1, b0);                        \
    __builtin_amdgcn_s_setprio(0); BAR;                                         \
    /* Ph4: Q(1,1) */                                                           \
    if (S2) STAGE(1, (U) + 2, 1);                                               \
    BAR;                                                                        \
    __builtin_amdgcn_s_setprio(1); MFMA_Q(1, 1, a1, b1);                        \
    __builtin_amdgcn_s_setprio(0);                                              \
    VMST; BAR;                                                                  \
  } while (0)

  // ---- prologue: tile0 all 4 half-tiles + tile1 {A0,B0,B1} (14 loads) ----
  STAGE(0, 0, 0); STAGE(1, 0, 0); STAGE(1, 0, 1); STAGE(0, 0, 1);
  STAGE(0, 1, 0); STAGE(1, 1, 0); STAGE(1, 1, 1);
  VMW6;   // tile0 fully landed; (1){A0,B0,B1} in flight -> steady state
  BAR;

#pragma unroll 1
  for (int i = 0; i < 31; ++i) {
    const int u0 = 2 * i;
    TILE(u0,     0,     1, 1, VMW6);
    TILE(u0 + 1, 16384, 1, 1, VMW6);
  }
  // tail: tile 62 stages only (63,A1) then drains; tile 63 stages nothing
  TILE(62, 0,     1, 0, VMW0);
  TILE(63, 16384, 0, 0, NOVM);

#undef TILE
#undef MFMA_Q
#undef READ_A0
#undef READ_A1
#undef READ_B0
#undef READ_B1
#undef STAGE
#undef LDA
#undef LDB

  // ---- epilogue: scale/bias fused C write (split-row M mapping) ----
  const float inv127 = 1.0f / 127.0f;
  const int n_base = bn * 256 + wc * 64;
#pragma unroll
  for (int nc = 0; nc < 4; ++nc) {
    const int n = n_base + nc * 16 + fr;
    const float sc = scales[n] * inv127;
    const float bz = bias[n];
#pragma unroll
    for (int rb = 0; rb < 8; ++rb) {
      const int m0 = bm * 256 + (rb >> 2) * 128 + wr * 64 + (rb & 3) * 16 + fq * 4;
      float* cp = C + (size_t)m0 * NDIM + n;
#pragma unroll
      for (int r = 0; r < 4; ++r)
        cp[(size_t)r * NDIM] = acc[rb][nc][r] * sc + bz;
    }
  }
}

// ---------------- fallback: fused conversion, reg staging (128^2) ----------------

__global__ __launch_bounds__(256) void gemm_fused(
    const float* __restrict__ X,
    const int* __restrict__ W,
    const float* __restrict__ scales,
    const float* __restrict__ bias,
    float* __restrict__ C) {
  __shared__ unsigned short As[128 * 32];
  __shared__ unsigned short Bs[128 * 32];

  const int tid = threadIdx.x;
  const int lane = tid & 63;
  const int wave = tid >> 6;
  const int wr = wave >> 1, wc = wave & 1;
  const int fr = lane & 15, fq = lane >> 4;

  int id = blockIdx.x;
  int swz = (id & 7) * 128 + (id >> 3);
  const int bm = swz >> 5, bn = swz & 31;

  const int r0 = tid >> 2;
  const int kc = (tid & 3) * 8;
  const size_t aBase = (size_t)(bm * 128 + r0) * KDIM + kc;
  const size_t bBase = (size_t)(bn * 128 + r0) * KDIM + kc;

  f32x4 acc[4][4] = {};

  for (int k0 = 0; k0 < KDIM; k0 += 32) {
    const float* xp = X + aBase + k0;
    const int*   wp = W + bBase + k0;
    fx4 x0 = *(const fx4*)xp;
    fx4 x1 = *(const fx4*)(xp + 4);
    fx4 x2 = *(const fx4*)(xp + (size_t)64 * KDIM);
    fx4 x3 = *(const fx4*)(xp + (size_t)64 * KDIM + 4);
    ix4 w0 = *(const ix4*)wp;
    ix4 w1 = *(const ix4*)(wp + 4);
    ix4 w2 = *(const ix4*)(wp + (size_t)64 * KDIM);
    ix4 w3 = *(const ix4*)(wp + (size_t)64 * KDIM + 4);

    usx8 ca, cb, cc, cd;
#pragma unroll
    for (int j = 0; j < 4; ++j) {
      ca[j] = f32_to_bf16_rne(x0[j]);  ca[j + 4] = f32_to_bf16_rne(x1[j]);
      cb[j] = f32_to_bf16_rne(x2[j]);  cb[j + 4] = f32_to_bf16_rne(x3[j]);
      cc[j] = f32_to_bf16_rne((float)w0[j]); cc[j + 4] = f32_to_bf16_rne((float)w1[j]);
      cd[j] = f32_to_bf16_rne((float)w2[j]); cd[j + 4] = f32_to_bf16_rne((float)w3[j]);
    }

    __syncthreads();
    *reinterpret_cast<usx8*>(As + tid * 8)        = ca;
    *reinterpret_cast<usx8*>(As + 2048 + tid * 8) = cb;
    *reinterpret_cast<usx8*>(Bs + tid * 8)        = cc;
    *reinterpret_cast<usx8*>(Bs + 2048 + tid * 8) = cd;
    __syncthreads();

    bf16x8 af[4], bfr[4];
    const unsigned short* ap = As + (wr * 64 + fr) * 32 + fq * 8;
    const unsigned short* bp = Bs + (wc * 64 + fr) * 32 + fq * 8;
#pragma unroll
    for (int i = 0; i < 4; ++i) {
      af[i]  = *reinterpret_cast<const bf16x8*>(ap + i * 512);
      bfr[i] = *reinterpret_cast<const bf16x8*>(bp + i * 512);
    }
#pragma unroll
    for (int im = 0; im < 4; ++im)
#pragma unroll
      for (int in_ = 0; in_ < 4; ++in_)
        acc[im][in_] = __builtin_amdgcn_mfma_f32_16x16x32_bf16(
            af[im], bfr[in_], acc[im][in_], 0, 0, 0);
  }

  const float inv127 = 1.0f / 127.0f;
#pragma unroll
  for (int in_ = 0; in_ < 4; ++in_) {
    int n = bn * 128 + wc * 64 + in_ * 16 + fr;
    float sc = scales[n] * inv127;
    float bz = bias[n];
#pragma unroll
    for (int im = 0; im < 4; ++im) {
      int m0 = bm * 128 + wr * 64 + im * 16 + fq * 4;
      float* cp = C + (size_t)m0 * NDIM + n;
#pragma unroll
      for (int r = 0; r < 4; ++r)
        cp[(size_t)r * NDIM] = acc[im][in_][r] * sc + bz;
    }
  }
}

// ---------------- host launch ----------------

extern "C" void kernel_launch(void* const* d_in, const int* in_sizes, int n_in,
                              void* d_out, int out_size, void* d_ws, size_t ws_size,
                              hipStream_t stream) {
  const float* x      = (const float*)d_in[0];
  const int*   w8     = (const int*)d_in[1];
  const float* scales = (const float*)d_in[2];
  // d_in[3] = weight_fp : unused by the reference
  const float* bias   = (const float*)d_in[4];
  float* out = (float*)d_out;

  const size_t xb_elems = (size_t)MDIM * KDIM;
  const size_t wb_elems = (size_t)NDIM * KDIM;
  const size_t need = (xb_elems + wb_elems) * sizeof(unsigned short);

  if (ws_size >= need) {
    unsigned short* xb = (unsigned short*)d_ws;
    unsigned short* wb = xb + xb_elems;
    int n8 = (int)(xb_elems / 8);
    cvt_both_kernel<<<2048, 256, 0, stream>>>(x, w8, xb, wb, n8);
    gemm_m201<<<256, 512, 0, stream>>>(xb, wb, scales, bias, out);
  } else {
    gemm_fused<<<1024, 256, 0, stream>>>(x, w8, scales, bias, out);
  }
}

// Round 7
// 152.464 us; speedup vs baseline: 1.0267x; 1.0267x over previous
//
#include <hip/hip_runtime.h>
#include <hip/hip_bf16.h>
#include <stdint.h>

// Problem constants (B=2, S=2048, IN=4096, OUT=4096)
#define MDIM 4096   // B*S
#define NDIM 4096   // OUT
#define KDIM 4096   // IN
#define NT   (KDIM / 64)   // 64 K-tiles of BK=64

typedef __attribute__((ext_vector_type(4))) float  f32x4;
typedef __attribute__((ext_vector_type(8))) short  bf16x8;
typedef __attribute__((ext_vector_type(4))) float  fx4;
typedef __attribute__((ext_vector_type(4))) int    ix4;
typedef __attribute__((ext_vector_type(8))) unsigned short usx8;

__device__ static inline unsigned short f32_to_bf16_rne(float f) {
  union { float f; unsigned int u; } v; v.f = f;
  unsigned int u = v.u;
  u += 0x7fffu + ((u >> 16) & 1u);
  return (unsigned short)(u >> 16);
}

__device__ static inline void gload_lds16(const unsigned short* g, unsigned short* l) {
  __builtin_amdgcn_global_load_lds((const __attribute__((address_space(1))) void*)g,
                                   (__attribute__((address_space(3))) void*)l,
                                   16, 0, 0);
}

// ---------------- merged conversion kernel ----------------

__global__ void cvt_both_kernel(const float* __restrict__ xin,
                                const int* __restrict__ win,
                                unsigned short* __restrict__ xout,
                                unsigned short* __restrict__ wout, int n8each) {
  int idx = blockIdx.x * blockDim.x + threadIdx.x;
  int stride = gridDim.x * blockDim.x;
  for (int i = idx; i < 2 * n8each; i += stride) {
    usx8 r;
    if (i < n8each) {
      const fx4* p = reinterpret_cast<const fx4*>(xin) + (size_t)i * 2;
      fx4 a = p[0], b = p[1];
      r[0] = f32_to_bf16_rne(a[0]); r[1] = f32_to_bf16_rne(a[1]);
      r[2] = f32_to_bf16_rne(a[2]); r[3] = f32_to_bf16_rne(a[3]);
      r[4] = f32_to_bf16_rne(b[0]); r[5] = f32_to_bf16_rne(b[1]);
      r[6] = f32_to_bf16_rne(b[2]); r[7] = f32_to_bf16_rne(b[3]);
      reinterpret_cast<usx8*>(xout)[i] = r;
    } else {
      int j = i - n8each;
      const ix4* p = reinterpret_cast<const ix4*>(win) + (size_t)j * 2;
      ix4 a = p[0], b = p[1];
      r[0] = f32_to_bf16_rne((float)a[0]); r[1] = f32_to_bf16_rne((float)a[1]);
      r[2] = f32_to_bf16_rne((float)a[2]); r[3] = f32_to_bf16_rne((float)a[3]);
      r[4] = f32_to_bf16_rne((float)b[0]); r[5] = f32_to_bf16_rne((float)b[1]);
      r[6] = f32_to_bf16_rne((float)b[2]); r[7] = f32_to_bf16_rne((float)b[3]);
      reinterpret_cast<usx8*>(wout)[j] = r;
    }
  }
}

// ---------------- 256x256 balanced-4-phase GEMM ----------------
// 512 threads = 8 waves (2M x 4N), split-row M mapping (R5 fix). BK=64.
// LDS = 2 dbuf x (256x64 A + 256x64 B) bf16 = 128 KiB. Grid 256 = 1 block/CU.
//
// Cycle model: per tile per CU, MFMA = 2484 cyc, LDS = 192 ds_read_b128 =
// ~2313 cyc (separate units). This schedule overlaps every read burst with
// an MFMA burst -- no exposed bottom read burst:
//   P1: read b1(cur)[4]            ; MFMA Q00(a0,b0)            ; BAR
//   P2: read a1(cur)[8]; stage A0  ; MFMA Q01(a0,b1) ; vmcnt(8) ; BAR
//   P3: read a0'(nxt)[8]; stage B0,B1; MFMA Q10(a1,b0); vmcnt(10); BAR
//   P4: read b0'(nxt)[4]; stage A1 ; MFMA Q11(a1,b1) ; vmcnt(8) ; BAR
// (a0'/b0' = NEXT tile's first fragments, read into the a0/b0 regs whose
// last MFMA use was P2/P3 -- no extra registers, no bottom burst.)
// lgkm: no explicit waits; every read is consumed by an MFMA exactly one
// phase later -> compiler inserts counted lgkmcnt via register deps.
//
// Region lifetimes (stage of region R allowed only after a barrier that all
// waves passed with their R-reads DRAINED -- drain = reg-dep consumption by
// the intervening MFMA):
//   A-half0[cur]: read u-1 P3 (a0'), consumed u P1 Q00 -> P1-end BAR -> stage @P2
//   B-half0/1[cur]: read u-1 P4 (b0') + u P1 (b1), consumed by P1/P2 MFMA
//                   -> P2-end BAR -> stage both halves @P3
//   A-half1[cur]: read u P2 (a1), consumed u P3 Q10 -> P3-end BAR -> stage @P4
// vmcnt ledger (2 gloads per STAGE; per-tile issue order A0 | B0,B1 | A1;
// each vmcnt is followed by a barrier -> cross-wave visible):
//   entering tile u: 8 outstanding = (u+1){A0,B0,B1,A1}
//   end-P2: 8+2=10 outstanding, need (u+1)A0 (oldest 2) -> vmcnt(8)
//   end-P3: 8+4=12,            need (u+1)B0            -> vmcnt(10)
//   end-P4: 10+2=12,           need (u+1){B1,A1}       -> vmcnt(8) -> leaves (u+2)'s 8
//   tail u=62 (no stages): vmcnt(6)/(4)/(0); u=63: none.
// LDS swizzle: slot q^(row&7), pre-swizzled global source (conflicts == 0).

__global__ __launch_bounds__(512, 2) void gemm_bal4(
    const unsigned short* __restrict__ A,    // [M][K] bf16 bits
    const unsigned short* __restrict__ Bw,   // [N][K] bf16 bits
    const float* __restrict__ scales,
    const float* __restrict__ bias,
    float* __restrict__ C) {
  __shared__ unsigned short Ash[32768];   // [2][256][64]
  __shared__ unsigned short Bsh[32768];

  const int tid = threadIdx.x;
  const int w   = tid >> 6;          // wave 0..7
  const int l   = tid & 63;
  const int wr  = w >> 2;            // 0..1 : M sub-block within each half
  const int wc  = w & 3;             // 0..3 : N quarter
  const int fr  = l & 15;            // fragment row
  const int fq  = l >> 4;            // fragment k-quarter

  // XCD-aware swizzle: 256 blocks, 256 % 8 == 0 -> simple bijective form
  const int id  = blockIdx.x;
  const int swz = (id & 7) * 32 + (id >> 3);
  const int bm  = swz >> 4, bn = swz & 15;

  const unsigned short* aorg = A  + (size_t)(bm * 256) * KDIM;
  const unsigned short* borg = Bw + (size_t)(bn * 256) * KDIM;

  // staging per-thread global offset (pre-swizzled source)
  const int lr = l >> 3;                 // row-in-octet 0..7
  const int ks = (l & 7) ^ lr;           // swizzled k-slot
  const size_t g_off = (size_t)(w * 16 + lr) * KDIM + (size_t)ks * 8;
  const int    s_off = w * 1024;         // lds elems (wave-uniform)

#define STAGE(isB, t, h) do {                                                   \
    const unsigned short* _g = ((isB) ? borg : aorg)                            \
        + (size_t)(h) * 128 * KDIM + (size_t)(t) * 64 + g_off;                  \
    unsigned short* _l = ((isB) ? Bsh : Ash)                                    \
        + (((t) & 1) * 16384 + (h) * 8192 + s_off);                             \
    gload_lds16(_g, _l);                                                        \
    gload_lds16(_g + 8 * KDIM, _l + 512);                                       \
  } while (0)

  // ds_read offsets (swizzled). Split-row M mapping: wave wr owns rows
  // {wr*64..+63} U {128+wr*64..+63}; a0 = half0 (rb 0..3), a1 = half1 (rb 8..11).
  const int arow = (wr * 64 + fr) * 64;
  const int brow = (wc * 64 + fr) * 64;
  const int q0 = ((fq)     ^ (fr & 7)) * 8;
  const int q1 = ((4 + fq) ^ (fr & 7)) * 8;

#define LDA(off, rb, qq) (*(const bf16x8*)(Ash + (off) + arow + (rb) * 1024 + (qq)))
#define LDB(off, nc, qq) (*(const bf16x8*)(Bsh + (off) + brow + (nc) * 1024 + (qq)))

#define BAR   __builtin_amdgcn_s_barrier()
#define VM10  asm volatile("s_waitcnt vmcnt(10)" ::: "memory")
#define VM8   asm volatile("s_waitcnt vmcnt(8)" ::: "memory")
#define VM6   asm volatile("s_waitcnt vmcnt(6)" ::: "memory")
#define VM4   asm volatile("s_waitcnt vmcnt(4)" ::: "memory")
#define VM0   asm volatile("s_waitcnt vmcnt(0)" ::: "memory")
#define NOVM  ((void)0)
#define SP1   __builtin_amdgcn_s_setprio(1)
#define SP0   __builtin_amdgcn_s_setprio(0)

  f32x4 acc[8][4] = {};
  bf16x8 a0[4][2], a1[4][2], b0[2][2], b1[2][2];

#define READ_A0(CO) { _Pragma("unroll") for (int rb = 0; rb < 4; ++rb) { a0[rb][0] = LDA(CO, rb, q0);     a0[rb][1] = LDA(CO, rb, q1); } }
#define READ_A1(CO) { _Pragma("unroll") for (int rb = 0; rb < 4; ++rb) { a1[rb][0] = LDA(CO, 8 + rb, q0); a1[rb][1] = LDA(CO, 8 + rb, q1); } }
#define READ_B0(CO) { _Pragma("unroll") for (int cb = 0; cb < 2; ++cb) { b0[cb][0] = LDB(CO, cb, q0);     b0[cb][1] = LDB(CO, cb, q1); } }
#define READ_B1(CO) { _Pragma("unroll") for (int cb = 0; cb < 2; ++cb) { b1[cb][0] = LDB(CO, 2 + cb, q0); b1[cb][1] = LDB(CO, 2 + cb, q1); } }

#define MFMA_Q(MH, NH, AA, BB)                                                  \
  { _Pragma("unroll") for (int rb = 0; rb < 4; ++rb)                            \
    _Pragma("unroll") for (int cb = 0; cb < 2; ++cb) {                          \
      acc[(MH)*4+rb][(NH)*2+cb] = __builtin_amdgcn_mfma_f32_16x16x32_bf16(      \
          AA[rb][0], BB[cb][0], acc[(MH)*4+rb][(NH)*2+cb], 0, 0, 0);            \
      acc[(MH)*4+rb][(NH)*2+cb] = __builtin_amdgcn_mfma_f32_16x16x32_bf16(      \
          AA[rb][1], BB[cb][1], acc[(MH)*4+rb][(NH)*2+cb], 0, 0, 0);            \
    } }

  // NX: read next tile's a0/b0 from nxt buffer. S2: stage tile U+2 into cur.
#define TILE(U, CO, NX, S2, V2, V3, V4) do {                                    \
    const int _nx = (CO) ^ 16384;                                               \
    /* P1: read b1(cur); MFMA Q00 */                                            \
    READ_B1(CO);                                                                \
    SP1; MFMA_Q(0, 0, a0, b0); SP0;                                             \
    BAR;                                                                        \
    /* P2: read a1(cur); stage (U+2)A0; MFMA Q01 */                             \
    READ_A1(CO);                                                                \
    if (S2) STAGE(0, (U) + 2, 0);                                               \
    SP1; MFMA_Q(0, 1, a0, b1); SP0;                                             \
    V2; BAR;                                                                    \
    /* P3: read a0'(nxt); stage (U+2)B0,B1; MFMA Q10 */                         \
    if (NX) READ_A0(_nx);                                                       \
    if (S2) { STAGE(1, (U) + 2, 0); STAGE(1, (U) + 2, 1); }                     \
    SP1; MFMA_Q(1, 0, a1, b0); SP0;                                             \
    V3; BAR;                                                                    \
    /* P4: read b0'(nxt); stage (U+2)A1; MFMA Q11 */                            \
    if (NX) READ_B0(_nx);                                                       \
    if (S2) STAGE(0, (U) + 2, 1);                                               \
    SP1; MFMA_Q(1, 1, a1, b1); SP0;                                             \
    V4; BAR;                                                                    \
  } while (0)

  // ---- prologue ----
  // Stage (0) and (1), each in ledger order {A0, B0, B1, A1}.
  STAGE(0, 0, 0); STAGE(1, 0, 0); STAGE(1, 0, 1); STAGE(0, 0, 1);
  STAGE(0, 1, 0); STAGE(1, 1, 0); STAGE(1, 1, 1); STAGE(0, 1, 1);
  VM8;   // tile 0 fully landed; (1)'s 8 in flight = steady-state entry
  BAR;
  // one-time exposed read of tile0's first fragments
  READ_A0(0); READ_B0(0);

#pragma unroll 2
  for (int u = 0; u < NT - 2; ++u) {
    const int cur = (u & 1) * 16384;
    TILE(u, cur, 1, 1, VM8, VM10, VM8);
  }
  TILE(NT - 2, 0,     1, 0, VM6,  VM4,  VM0);    // u=62: no stages, drain ramp
  TILE(NT - 1, 16384, 0, 0, NOVM, NOVM, NOVM);   // u=63: last tile

#undef TILE
#undef MFMA_Q
#undef READ_A0
#undef READ_A1
#undef READ_B0
#undef READ_B1
#undef STAGE
#undef LDA
#undef LDB

  // ---- epilogue: scale/bias fused C write (split-row M mapping) ----
  const float inv127 = 1.0f / 127.0f;
  const int n_base = bn * 256 + wc * 64;
#pragma unroll
  for (int nc = 0; nc < 4; ++nc) {
    const int n = n_base + nc * 16 + fr;
    const float sc = scales[n] * inv127;
    const float bz = bias[n];
#pragma unroll
    for (int rb = 0; rb < 8; ++rb) {
      const int m0 = bm * 256 + (rb >> 2) * 128 + wr * 64 + (rb & 3) * 16 + fq * 4;
      float* cp = C + (size_t)m0 * NDIM + n;
#pragma unroll
      for (int r = 0; r < 4; ++r)
        cp[(size_t)r * NDIM] = acc[rb][nc][r] * sc + bz;
    }
  }
}

// ---------------- fallback: fused conversion, reg staging (128^2) ----------------

__global__ __launch_bounds__(256) void gemm_fused(
    const float* __restrict__ X,
    const int* __restrict__ W,
    const float* __restrict__ scales,
    const float* __restrict__ bias,
    float* __restrict__ C) {
  __shared__ unsigned short As[128 * 32];
  __shared__ unsigned short Bs[128 * 32];

  const int tid = threadIdx.x;
  const int lane = tid & 63;
  const int wave = tid >> 6;
  const int wr = wave >> 1, wc = wave & 1;
  const int fr = lane & 15, fq = lane >> 4;

  int id = blockIdx.x;
  int swz = (id & 7) * 128 + (id >> 3);
  const int bm = swz >> 5, bn = swz & 31;

  const int r0 = tid >> 2;
  const int kc = (tid & 3) * 8;
  const size_t aBase = (size_t)(bm * 128 + r0) * KDIM + kc;
  const size_t bBase = (size_t)(bn * 128 + r0) * KDIM + kc;

  f32x4 acc[4][4] = {};

  for (int k0 = 0; k0 < KDIM; k0 += 32) {
    const float* xp = X + aBase + k0;
    const int*   wp = W + bBase + k0;
    fx4 x0 = *(const fx4*)xp;
    fx4 x1 = *(const fx4*)(xp + 4);
    fx4 x2 = *(const fx4*)(xp + (size_t)64 * KDIM);
    fx4 x3 = *(const fx4*)(xp + (size_t)64 * KDIM + 4);
    ix4 w0 = *(const ix4*)wp;
    ix4 w1 = *(const ix4*)(wp + 4);
    ix4 w2 = *(const ix4*)(wp + (size_t)64 * KDIM);
    ix4 w3 = *(const ix4*)(wp + (size_t)64 * KDIM + 4);

    usx8 ca, cb, cc, cd;
#pragma unroll
    for (int j = 0; j < 4; ++j) {
      ca[j] = f32_to_bf16_rne(x0[j]);  ca[j + 4] = f32_to_bf16_rne(x1[j]);
      cb[j] = f32_to_bf16_rne(x2[j]);  cb[j + 4] = f32_to_bf16_rne(x3[j]);
      cc[j] = f32_to_bf16_rne((float)w0[j]); cc[j + 4] = f32_to_bf16_rne((float)w1[j]);
      cd[j] = f32_to_bf16_rne((float)w2[j]); cd[j + 4] = f32_to_bf16_rne((float)w3[j]);
    }

    __syncthreads();
    *reinterpret_cast<usx8*>(As + tid * 8)        = ca;
    *reinterpret_cast<usx8*>(As + 2048 + tid * 8) = cb;
    *reinterpret_cast<usx8*>(Bs + tid * 8)        = cc;
    *reinterpret_cast<usx8*>(Bs + 2048 + tid * 8) = cd;
    __syncthreads();

    bf16x8 af[4], bfr[4];
    const unsigned short* ap = As + (wr * 64 + fr) * 32 + fq * 8;
    const unsigned short* bp = Bs + (wc * 64 + fr) * 32 + fq * 8;
#pragma unroll
    for (int i = 0; i < 4; ++i) {
      af[i]  = *reinterpret_cast<const bf16x8*>(ap + i * 512);
      bfr[i] = *reinterpret_cast<const bf16x8*>(bp + i * 512);
    }
#pragma unroll
    for (int im = 0; im < 4; ++im)
#pragma unroll
      for (int in_ = 0; in_ < 4; ++in_)
        acc[im][in_] = __builtin_amdgcn_mfma_f32_16x16x32_bf16(
            af[im], bfr[in_], acc[im][in_], 0, 0, 0);
  }

  const float inv127 = 1.0f / 127.0f;
#pragma unroll
  for (int in_ = 0; in_ < 4; ++in_) {
    int n = bn * 128 + wc * 64 + in_ * 16 + fr;
    float sc = scales[n] * inv127;
    float bz = bias[n];
#pragma unroll
    for (int im = 0; im < 4; ++im) {
      int m0 = bm * 128 + wr * 64 + im * 16 + fq * 4;
      float* cp = C + (size_t)m0 * NDIM + n;
#pragma unroll
      for (int r = 0; r < 4; ++r)
        cp[(size_t)r * NDIM] = acc[im][in_][r] * sc + bz;
    }
  }
}

// ---------------- host launch ----------------

extern "C" void kernel_launch(void* const* d_in, const int* in_sizes, int n_in,
                              void* d_out, int out_size, void* d_ws, size_t ws_size,
                              hipStream_t stream) {
  const float* x      = (const float*)d_in[0];
  const int*   w8     = (const int*)d_in[1];
  const float* scales = (const float*)d_in[2];
  // d_in[3] = weight_fp : unused by the reference
  const float* bias   = (const float*)d_in[4];
  float* out = (float*)d_out;

  const size_t xb_elems = (size_t)MDIM * KDIM;
  const size_t wb_elems = (size_t)NDIM * KDIM;
  const size_t need = (xb_elems + wb_elems) * sizeof(unsigned short);

  if (ws_size >= need) {
    unsigned short* xb = (unsigned short*)d_ws;
    unsigned short* wb = xb + xb_elems;
    int n8 = (int)(xb_elems / 8);
    cvt_both_kernel<<<2048, 256, 0, stream>>>(x, w8, xb, wb, n8);
    gemm_bal4<<<256, 512, 0, stream>>>(xb, wb, scales, bias, out);
  } else {
    gemm_fused<<<1024, 256, 0, stream>>>(x, w8, scales, bias, out);
  }
}

// Round 8
// 95.214 us; speedup vs baseline: 1.6440x; 1.6013x over previous
//
#include <hip/hip_runtime.h>
#include <hip/hip_bf16.h>
#include <stdint.h>

// Problem constants (B=2, S=2048, IN=4096, OUT=4096)
#define MDIM 4096   // B*S
#define NDIM 4096   // OUT
#define KDIM 4096   // IN
#define NT   (KDIM / 64)   // 64 K-tiles of 64 i8 elements

typedef __attribute__((ext_vector_type(4))) float  f32x4;
typedef __attribute__((ext_vector_type(4))) int    i32x4;
typedef __attribute__((ext_vector_type(8))) short  bf16x8;
typedef __attribute__((ext_vector_type(4))) float  fx4;
typedef __attribute__((ext_vector_type(4))) int    ix4;
typedef __attribute__((ext_vector_type(8))) unsigned short usx8;

__device__ static inline unsigned short f32_to_bf16_rne(float f) {
  union { float f; unsigned int u; } v; v.f = f;
  unsigned int u = v.u;
  u += 0x7fffu + ((u >> 16) & 1u);
  return (unsigned short)(u >> 16);
}

__device__ static inline void gload_lds16(const void* g, void* l) {
  __builtin_amdgcn_global_load_lds((const __attribute__((address_space(1))) void*)g,
                                   (__attribute__((address_space(3))) void*)l,
                                   16, 0, 0);
}

// i8 MFMA via inline asm (D,A,B,C; D==C via "+v"). Register deps give the
// compiler exact lgkmcnt insertion for LDS-sourced operands.
__device__ static inline void mfma_i8(i32x4& d, const i32x4& a, const i32x4& b) {
  asm("v_mfma_i32_16x16x64_i8 %0, %1, %2, %0" : "+v"(d) : "v"(a), "v"(b));
}

// ---------------- prepass: quantize x (per-row) + pack w ----------------
// blocks 0..MDIM-1: x row -> absmax -> int8, xs[m] = absmax/127
// blocks MDIM..MDIM+NDIM-1: w row (int32 0..126) -> int8 pack

__global__ __launch_bounds__(256) void quant_both(
    const float* __restrict__ x, const int* __restrict__ w8,
    signed char* __restrict__ xq, signed char* __restrict__ wq,
    float* __restrict__ xs) {
  const int bid = blockIdx.x, t = threadIdx.x;
  if (bid < MDIM) {
    const float* row = x + (size_t)bid * KDIM + t * 16;
    fx4 v0 = *(const fx4*)(row);
    fx4 v1 = *(const fx4*)(row + 4);
    fx4 v2 = *(const fx4*)(row + 8);
    fx4 v3 = *(const fx4*)(row + 12);
    float am = 0.0f;
#pragma unroll
    for (int j = 0; j < 4; ++j) {
      am = fmaxf(am, fmaxf(__builtin_fabsf(v0[j]), __builtin_fabsf(v1[j])));
      am = fmaxf(am, fmaxf(__builtin_fabsf(v2[j]), __builtin_fabsf(v3[j])));
    }
#pragma unroll
    for (int off = 32; off; off >>= 1) am = fmaxf(am, __shfl_xor(am, off));
    __shared__ float wm[4];
    if ((t & 63) == 0) wm[t >> 6] = am;
    __syncthreads();
    am = fmaxf(fmaxf(wm[0], wm[1]), fmaxf(wm[2], wm[3]));
    am = fmaxf(am, 1e-20f);
    const float qs = 127.0f / am;
    int q[16];
#pragma unroll
    for (int j = 0; j < 4; ++j) {
      q[j]      = (int)rintf(v0[j] * qs);
      q[4 + j]  = (int)rintf(v1[j] * qs);
      q[8 + j]  = (int)rintf(v2[j] * qs);
      q[12 + j] = (int)rintf(v3[j] * qs);
    }
    i32x4 pk;
#pragma unroll
    for (int j = 0; j < 4; ++j)
      pk[j] = (q[4*j] & 255) | ((q[4*j+1] & 255) << 8) |
              ((q[4*j+2] & 255) << 16) | ((q[4*j+3] & 255) << 24);
    *(i32x4*)(xq + (size_t)bid * KDIM + t * 16) = pk;
    if (t == 0) xs[bid] = am * (1.0f / 127.0f);
  } else {
    const int n = bid - MDIM;
    const int* row = w8 + (size_t)n * KDIM + t * 16;
    ix4 w0 = *(const ix4*)(row);
    ix4 w1 = *(const ix4*)(row + 4);
    ix4 w2 = *(const ix4*)(row + 8);
    ix4 w3 = *(const ix4*)(row + 12);
    i32x4 pk;
    pk[0] = (w0[0] & 255) | ((w0[1] & 255) << 8) | ((w0[2] & 255) << 16) | ((w0[3] & 255) << 24);
    pk[1] = (w1[0] & 255) | ((w1[1] & 255) << 8) | ((w1[2] & 255) << 16) | ((w1[3] & 255) << 24);
    pk[2] = (w2[0] & 255) | ((w2[1] & 255) << 8) | ((w2[2] & 255) << 16) | ((w2[3] & 255) << 24);
    pk[3] = (w3[0] & 255) | ((w3[1] & 255) << 8) | ((w3[2] & 255) << 16) | ((w3[3] & 255) << 24);
    *(i32x4*)(wq + (size_t)n * KDIM + t * 16) = pk;
  }
}

// ---------------- 256x256 int8 GEMM (R4 2-barrier schedule) ----------------
// 512 threads = 8 waves (2M x 4N). Per-wave output 128x64. K-step = 64 i8.
// LDS = 2 dbuf x (256x64 A + 256x64 B) i8 = 64 KiB.
// mfma_i32_16x16x64_i8: per-lane A/B frag = 16 contiguous i8 (one b128):
//   lane l: row l&15, k = 16*(l>>4)+j. C/D: col=lane&15, row=(lane>>4)*4+reg
//   (dtype-independent, m121-128).
// Tile schedule (R4-verified 2-barrier, i8 sizing):
//   [boundary: read a0(4),b0(2) from cur]
//   Phase A: read b1(2),a1(4); 16 MFMA (a0 x {b0,b1}); lgkmcnt(0); BAR
//   Phase B: stage tile u+2 (4 gloads); 16 MFMA (a1 x {b0,b1});
//            vmcnt(4); BAR; read-ahead a0,b0 from nxt
// Region safety: all 12 ds_reads of cur drained by Phase-A lgkmcnt(0)+BAR
//   before any stage into cur; cur re-read only at tile u+2, gated by tile
//   u+1's vmcnt(4)+BAR. vmcnt ledger: entering u: 4 outstanding ((u+1)'s);
//   +4 in Phase B; vmcnt(4) leaves (u+2)'s. Tail u=NT-2: no stage, vmcnt(0).
// LDS bank swizzle for 64B rows (row stride = 16 banks): slot' = s^((row>>1)&3)
//   -> 16 lanes hit 8 distinct 4-bank runs = 2-way (free). Staging pre-swizzle:
//   ks = (l&3)^((l>>3)&3) on the GLOBAL source; linear gload_lds dest (rule 21).

__global__ __launch_bounds__(512, 2) void gemm_i8(
    const signed char* __restrict__ Aq,    // [M][K] i8
    const signed char* __restrict__ Wq,    // [N][K] i8
    const float* __restrict__ xs,          // [M] row scale = absmax/127
    const float* __restrict__ scales,      // [N]
    const float* __restrict__ bias,
    float* __restrict__ C) {
  __shared__ signed char Ash[2 * 16384];   // [2][256][64]
  __shared__ signed char Bsh[2 * 16384];

  const int tid = threadIdx.x;
  const int w   = tid >> 6;
  const int l   = tid & 63;
  const int wr  = w >> 2;            // 0..1 : M half
  const int wc  = w & 3;             // 0..3 : N quarter
  const int fr  = l & 15;
  const int fq  = l >> 4;

  // XCD-aware swizzle: 256 blocks, 256 % 8 == 0
  const int id  = blockIdx.x;
  const int swz = (id & 7) * 32 + (id >> 3);
  const int bm  = swz >> 4, bn = swz & 15;

  const signed char* aorg = Aq + (size_t)(bm * 256) * KDIM;
  const signed char* borg = Wq + (size_t)(bn * 256) * KDIM;

  // staging: wave covers 16 rows of 64B per gload; pre-swizzled global slot
  const int lr = l >> 2;                       // row-in-wave-chunk 0..15
  const int ks = (l & 3) ^ ((l >> 3) & 3);     // swizzled 16B slot
  const size_t g_off = (size_t)(w * 16 + lr) * KDIM + (size_t)ks * 16;
  const int    s_off = w * 1024;               // bytes, wave-uniform

#define STAGE(isB, t, h) do {                                                   \
    const signed char* _g = ((isB) ? borg : aorg)                               \
        + (size_t)(h) * 128 * KDIM + (size_t)(t) * 64 + g_off;                  \
    signed char* _l = ((isB) ? Bsh : Ash)                                       \
        + (((t) & 1) * 16384 + (h) * 8192 + s_off);                             \
    gload_lds16(_g, _l);                                                        \
  } while (0)

  // ds_read offsets (swizzled): row = (wr*128 | wc*64) + sub*16 + fr;
  // (row>>1)&3 == (fr>>1)&3 for all sub -> per-lane constant slot.
  const int arow = (wr * 128 + fr) * 64;
  const int brow = (wc * 64  + fr) * 64;
  const int sl   = (fq ^ ((fr >> 1) & 3)) * 16;

#define LDA(off, rb) (*(const i32x4*)(Ash + (off) + arow + (rb) * 1024 + sl))
#define LDB(off, nc) (*(const i32x4*)(Bsh + (off) + brow + (nc) * 1024 + sl))

#define BAR   __builtin_amdgcn_s_barrier()
#define LGKM0 asm volatile("s_waitcnt lgkmcnt(0)" ::: "memory")
#define VM4   asm volatile("s_waitcnt vmcnt(4)" ::: "memory")
#define VM0   asm volatile("s_waitcnt vmcnt(0)" ::: "memory")
#define NOVM  ((void)0)
#define SP1   __builtin_amdgcn_s_setprio(1)
#define SP0   __builtin_amdgcn_s_setprio(0)

  i32x4 acc[8][4] = {};
  i32x4 a0[4], a1[4], b0[2], b1[2];

#define READ_A0(CO) { _Pragma("unroll") for (int rb = 0; rb < 4; ++rb) a0[rb] = LDA(CO, rb); }
#define READ_A1(CO) { _Pragma("unroll") for (int rb = 0; rb < 4; ++rb) a1[rb] = LDA(CO, 4 + rb); }
#define READ_B0(CO) { _Pragma("unroll") for (int cb = 0; cb < 2; ++cb) b0[cb] = LDB(CO, cb); }
#define READ_B1(CO) { _Pragma("unroll") for (int cb = 0; cb < 2; ++cb) b1[cb] = LDB(CO, 2 + cb); }

#define MFMA_Q(MH, NH, AA, BB)                                                  \
  { _Pragma("unroll") for (int rb = 0; rb < 4; ++rb)                            \
    _Pragma("unroll") for (int cb = 0; cb < 2; ++cb)                            \
      mfma_i8(acc[(MH)*4+rb][(NH)*2+cb], AA[rb], BB[cb]); }

#define TILE(U, CO, NX, S2, VMST) do {                                          \
    const int _nx = (CO) ^ 16384;                                               \
    /* Phase A: pre-read b1,a1 ; MFMA a0 x {b0,b1} */                           \
    READ_B1(CO); READ_A1(CO);                                                   \
    SP1; MFMA_Q(0, 0, a0, b0); MFMA_Q(0, 1, a0, b1); SP0;                       \
    LGKM0; BAR;                                                                 \
    /* Phase B: stage (U+2) into cur ; MFMA a1 x {b0,b1} */                     \
    if (S2) { STAGE(0, (U) + 2, 0); STAGE(0, (U) + 2, 1);                       \
              STAGE(1, (U) + 2, 0); STAGE(1, (U) + 2, 1); }                     \
    SP1; MFMA_Q(1, 0, a1, b0); MFMA_Q(1, 1, a1, b1); SP0;                       \
    VMST; BAR;                                                                  \
    if (NX) { READ_A0(_nx); READ_B0(_nx); }                                     \
  } while (0)

  // ---- prologue: stage t0 + t1 (8 gloads), land t0, boundary read ----
  STAGE(0, 0, 0); STAGE(0, 0, 1); STAGE(1, 0, 0); STAGE(1, 0, 1);
  STAGE(0, 1, 0); STAGE(0, 1, 1); STAGE(1, 1, 0); STAGE(1, 1, 1);
  VM4;   // t0 landed; t1's 4 in flight = steady-state entry
  BAR;
  READ_A0(0); READ_B0(0);

#pragma unroll 2
  for (int u = 0; u < NT - 2; ++u) {
    const int cur = (u & 1) * 16384;
    TILE(u, cur, 1, 1, VM4);
  }
  TILE(NT - 2, 0,     1, 0, VM0);
  TILE(NT - 1, 16384, 0, 0, NOVM);

#undef TILE
#undef MFMA_Q
#undef READ_A0
#undef READ_A1
#undef READ_B0
#undef READ_B1
#undef STAGE
#undef LDA
#undef LDB

  // ---- epilogue: out = acc * xs[m] * (scales[n]/127) + bias[n] ----
  const float inv127 = 1.0f / 127.0f;
  const int n_base = bn * 256 + wc * 64;
  const int m_base = bm * 256 + wr * 128 + fq * 4;
  float xr[8][4];
#pragma unroll
  for (int rb = 0; rb < 8; ++rb)
#pragma unroll
    for (int r = 0; r < 4; ++r) xr[rb][r] = xs[m_base + rb * 16 + r];
#pragma unroll
  for (int nc = 0; nc < 4; ++nc) {
    const int n = n_base + nc * 16 + fr;
    const float sw = scales[n] * inv127;
    const float bz = bias[n];
#pragma unroll
    for (int rb = 0; rb < 8; ++rb) {
      float* cp = C + (size_t)(m_base + rb * 16) * NDIM + n;
#pragma unroll
      for (int r = 0; r < 4; ++r)
        cp[(size_t)r * NDIM] = (float)acc[rb][nc][r] * (xr[rb][r] * sw) + bz;
    }
  }
}

// ---------------- fallback: fused conversion, reg staging (128^2 bf16) ----------------

__global__ __launch_bounds__(256) void gemm_fused(
    const float* __restrict__ X,
    const int* __restrict__ W,
    const float* __restrict__ scales,
    const float* __restrict__ bias,
    float* __restrict__ C) {
  __shared__ unsigned short As[128 * 32];
  __shared__ unsigned short Bs[128 * 32];

  const int tid = threadIdx.x;
  const int lane = tid & 63;
  const int wave = tid >> 6;
  const int wr = wave >> 1, wc = wave & 1;
  const int fr = lane & 15, fq = lane >> 4;

  int id = blockIdx.x;
  int swz = (id & 7) * 128 + (id >> 3);
  const int bm = swz >> 5, bn = swz & 31;

  const int r0 = tid >> 2;
  const int kc = (tid & 3) * 8;
  const size_t aBase = (size_t)(bm * 128 + r0) * KDIM + kc;
  const size_t bBase = (size_t)(bn * 128 + r0) * KDIM + kc;

  f32x4 acc[4][4] = {};

  for (int k0 = 0; k0 < KDIM; k0 += 32) {
    const float* xp = X + aBase + k0;
    const int*   wp = W + bBase + k0;
    fx4 x0 = *(const fx4*)xp;
    fx4 x1 = *(const fx4*)(xp + 4);
    fx4 x2 = *(const fx4*)(xp + (size_t)64 * KDIM);
    fx4 x3 = *(const fx4*)(xp + (size_t)64 * KDIM + 4);
    ix4 w0 = *(const ix4*)wp;
    ix4 w1 = *(const ix4*)(wp + 4);
    ix4 w2 = *(const ix4*)(wp + (size_t)64 * KDIM);
    ix4 w3 = *(const ix4*)(wp + (size_t)64 * KDIM + 4);

    usx8 ca, cb, cc, cd;
#pragma unroll
    for (int j = 0; j < 4; ++j) {
      ca[j] = f32_to_bf16_rne(x0[j]);  ca[j + 4] = f32_to_bf16_rne(x1[j]);
      cb[j] = f32_to_bf16_rne(x2[j]);  cb[j + 4] = f32_to_bf16_rne(x3[j]);
      cc[j] = f32_to_bf16_rne((float)w0[j]); cc[j + 4] = f32_to_bf16_rne((float)w1[j]);
      cd[j] = f32_to_bf16_rne((float)w2[j]); cd[j + 4] = f32_to_bf16_rne((float)w3[j]);
    }

    __syncthreads();
    *reinterpret_cast<usx8*>(As + tid * 8)        = ca;
    *reinterpret_cast<usx8*>(As + 2048 + tid * 8) = cb;
    *reinterpret_cast<usx8*>(Bs + tid * 8)        = cc;
    *reinterpret_cast<usx8*>(Bs + 2048 + tid * 8) = cd;
    __syncthreads();

    bf16x8 af[4], bfr[4];
    const unsigned short* ap = As + (wr * 64 + fr) * 32 + fq * 8;
    const unsigned short* bp = Bs + (wc * 64 + fr) * 32 + fq * 8;
#pragma unroll
    for (int i = 0; i < 4; ++i) {
      af[i]  = *reinterpret_cast<const bf16x8*>(ap + i * 512);
      bfr[i] = *reinterpret_cast<const bf16x8*>(bp + i * 512);
    }
#pragma unroll
    for (int im = 0; im < 4; ++im)
#pragma unroll
      for (int in_ = 0; in_ < 4; ++in_)
        acc[im][in_] = __builtin_amdgcn_mfma_f32_16x16x32_bf16(
            af[im], bfr[in_], acc[im][in_], 0, 0, 0);
  }

  const float inv127 = 1.0f / 127.0f;
#pragma unroll
  for (int in_ = 0; in_ < 4; ++in_) {
    int n = bn * 128 + wc * 64 + in_ * 16 + fr;
    float sc = scales[n] * inv127;
    float bz = bias[n];
#pragma unroll
    for (int im = 0; im < 4; ++im) {
      int m0 = bm * 128 + wr * 64 + im * 16 + fq * 4;
      float* cp = C + (size_t)m0 * NDIM + n;
#pragma unroll
      for (int r = 0; r < 4; ++r)
        cp[(size_t)r * NDIM] = acc[im][in_][r] * sc + bz;
    }
  }
}

// ---------------- host launch ----------------

extern "C" void kernel_launch(void* const* d_in, const int* in_sizes, int n_in,
                              void* d_out, int out_size, void* d_ws, size_t ws_size,
                              hipStream_t stream) {
  const float* x      = (const float*)d_in[0];
  const int*   w8     = (const int*)d_in[1];
  const float* scales = (const float*)d_in[2];
  // d_in[3] = weight_fp : unused by the reference
  const float* bias   = (const float*)d_in[4];
  float* out = (float*)d_out;

  const size_t xq_bytes = (size_t)MDIM * KDIM;           // 16.7 MB
  const size_t wq_bytes = (size_t)NDIM * KDIM;           // 16.7 MB
  const size_t xs_bytes = (size_t)MDIM * sizeof(float);
  const size_t need = xq_bytes + wq_bytes + xs_bytes;

  if (ws_size >= need) {
    signed char* xq = (signed char*)d_ws;
    signed char* wq = xq + xq_bytes;
    float*       xs = (float*)(wq + wq_bytes);
    quant_both<<<MDIM + NDIM, 256, 0, stream>>>(x, w8, xq, wq, xs);
    gemm_i8<<<256, 512, 0, stream>>>(xq, wq, xs, scales, bias, out);
  } else {
    gemm_fused<<<1024, 256, 0, stream>>>(x, w8, scales, bias, out);
  }
}